// Round 1
// baseline (93.599 us; speedup 1.0000x reference)
//
#include <hip/hip_runtime.h>

#define B_ 4096
#define D_ 512
#define STEPS_ 50

// 2-wide f32 vector -> gfx950 full-rate packed ops (v_pk_fma_f32 / v_pk_mul_f32).
typedef float v2f __attribute__((ext_vector_type(2)));

// DPP add-reduce step; bound_ctrl=true -> out-of-row source reads 0.
#define DPP_ADD(x, ctrl) \
    ((x) + __int_as_float(__builtin_amdgcn_update_dpp( \
        0, __float_as_int(x), (ctrl), 0xf, 0xf, true)))

// Full wave64 sum: row_shr tree + row_bcast15/31, total lands in lane 63,
// readlane makes it uniform. No LDS crossbar (vs ds_bpermute in prior rev).
__device__ __forceinline__ float wave64_sum(float x) {
    x = DPP_ADD(x, 0x111);  // row_shr:1
    x = DPP_ADD(x, 0x112);  // row_shr:2
    x = DPP_ADD(x, 0x114);  // row_shr:4
    x = DPP_ADD(x, 0x118);  // row_shr:8
    x = DPP_ADD(x, 0x142);  // row_bcast:15
    x = DPP_ADD(x, 0x143);  // row_bcast:31
    return __int_as_float(__builtin_amdgcn_readlane(__float_as_int(x), 63));
}

// coef = (p - t)*p*(1-p), p = sigmoid(z); p(1-p) = e*p^2 with e = exp(-z).
__device__ __forceinline__ float coef_from_z(float z, float t) {
    const float e = __expf(-z);
    const float q = __builtin_amdgcn_rcpf(1.0f + e);
    return (q - t) * (e * (q * q));
}

__device__ __forceinline__ v2f mk2(float a, float b) { v2f r; r.x = a; r.y = b; return r; }

// ONE ROW PER WAVE: 64 lanes x 8 elems. 4096 waves = 4 waves/SIMD (vs 1
// before) so dependent-chain latency (FMA, rsq, the reduce+sigmoid chain)
// hides behind other waves' issue. Elementwise Adam math in v2f so the
// backend emits v_pk_fma_f32/v_pk_mul_f32 (halves VALU issue cycles).
// 4 independent waves per 256-thread block, no LDS, no __syncthreads.
__global__ __launch_bounds__(256, 4) void adam_row_kernel(
    const float* __restrict__ s,
    const float* __restrict__ tgt,
    const float* __restrict__ W,
    const float* __restrict__ bias_p,
    float* __restrict__ out)
{
    const int lane = threadIdx.x & 63;
    const int row  = blockIdx.x * 4 + (threadIdx.x >> 6);

    // Lane-indexed An table: An[t] = -(lr*0.1/(1-0.9^(t+1)))/sqrt(0.001/(1-0.999^(t+1)))
    float vAn;
    {
        const float t1 = (float)(lane + 1);
        const float p1 = exp2f(t1 * -0.15200309344505f);    // 0.9^(t+1)
        const float p2 = exp2f(t1 * -0.00144345345258f);    // 0.999^(t+1)
        vAn = (-0.0316227766017f * __builtin_amdgcn_sqrtf(1.0f - p2)) *
              __builtin_amdgcn_rcpf(1.0f - p1);
    }

    const float c_mse = 0x1p-11f;          // 2/B, exact
    const float K     = 2048.0f;           // 1/c_mse
    const float c_l1  = 0x1p-21f;          // 1/(B*D)

    const float4* W4  = (const float4*)W;
    const float4* sr4 = (const float4*)(s + (size_t)row * D_);

    const float4 w0 = W4[lane], w1 = W4[lane + 64];
    const float4 e0 = sr4[lane], e1 = sr4[lane + 64];

    v2f ws[4], sv[4], M[4], V[4], dl[4];
    ws[0] = mk2(w0.x, w0.y) * c_mse;  ws[1] = mk2(w0.z, w0.w) * c_mse;
    ws[2] = mk2(w1.x, w1.y) * c_mse;  ws[3] = mk2(w1.z, w1.w) * c_mse;
    sv[0] = mk2(e0.x, e0.y);          sv[1] = mk2(e0.z, e0.w);
    sv[2] = mk2(e1.x, e1.y);          sv[3] = mk2(e1.z, e1.w);

    // zb = s_row.W + b (ws carries c_mse; K undoes it for the dot).
    float zb;
    {
        v2f a = sv[0] * ws[0];
        a = sv[1] * ws[1] + a;
        a = sv[2] * ws[2] + a;
        a = sv[3] * ws[3] + a;
        zb = fmaf(K, wave64_sum(a.x + a.y), bias_p[0]);
    }
    const float tg = tgt[row];

    float vc = coef_from_z(zb, tg);

    // ---- step 0 peeled: dl == 0 -> L1 term 0; V seeded +1e-30 ----
    {
        const float An0 = __int_as_float(
            __builtin_amdgcn_readlane(__float_as_int(vAn), 0));
        v2f acc = mk2(0.0f, 0.0f);
#pragma unroll
        for (int k = 0; k < 4; ++k) {
            const v2f g = vc * ws[k];
            M[k] = g;
            V[k] = g * g + 1e-30f;
            v2f r;
            r.x = __builtin_amdgcn_rsqf(V[k].x);
            r.y = __builtin_amdgcn_rsqf(V[k].y);
            dl[k] = (An0 * g) * r;
            acc = dl[k] * ws[k] + acc;
        }
        const float z = fmaf(K, wave64_sum(acc.x + acc.y), zb);
        vc = coef_from_z(z, tg);
    }

    // ---- steps 1..49 ----
#pragma unroll 1
    for (int step = 1; step < STEPS_; ++step) {
        const float An = __int_as_float(
            __builtin_amdgcn_readlane(__float_as_int(vAn), step));
        v2f acc = mk2(0.0f, 0.0f);
#pragma unroll
        for (int k = 0; k < 4; ++k) {
            v2f sgn;
            sgn.x = __builtin_copysignf(c_l1, dl[k].x);
            sgn.y = __builtin_copysignf(c_l1, dl[k].y);
            const v2f g = vc * ws[k] + sgn;          // pk_fma (vc splat via op_sel)
            M[k] = 0.9f * M[k] + g;                  // pk_fma
            V[k] = 0.999f * V[k] + g * g;            // pk_mul + pk_fma
            v2f r;
            r.x = __builtin_amdgcn_rsqf(V[k].x);
            r.y = __builtin_amdgcn_rsqf(V[k].y);
            dl[k] = (An * M[k]) * r + dl[k];         // pk_mul + pk_fma
            acc = dl[k] * ws[k] + acc;               // pk_fma
        }
        if (step != STEPS_ - 1) {   // step 49's dot is never consumed
            const float z = fmaf(K, wave64_sum(acc.x + acc.y), zb);
            vc = coef_from_z(z, tg);
        }
    }

    // Epilogue: x = s + dl (s kept in registers).
    float4* o4 = (float4*)(out + (size_t)row * D_);
    float4 o0, o1;
    o0.x = sv[0].x + dl[0].x; o0.y = sv[0].y + dl[0].y;
    o0.z = sv[1].x + dl[1].x; o0.w = sv[1].y + dl[1].y;
    o1.x = sv[2].x + dl[2].x; o1.y = sv[2].y + dl[2].y;
    o1.z = sv[3].x + dl[3].x; o1.w = sv[3].y + dl[3].y;
    o4[lane]      = o0;
    o4[lane + 64] = o1;
}

extern "C" void kernel_launch(void* const* d_in, const int* in_sizes, int n_in,
                              void* d_out, int out_size, void* d_ws, size_t ws_size,
                              hipStream_t stream) {
    const float* s    = (const float*)d_in[0];  // [4096, 512]
    const float* tgt  = (const float*)d_in[1];  // [4096, 1]
    const float* W    = (const float*)d_in[2];  // [1, 512]
    const float* bias = (const float*)d_in[3];  // [1]
    float* out = (float*)d_out;                 // [4096, 512]

    adam_row_kernel<<<dim3(B_ / 4), dim3(256), 0, stream>>>(s, tgt, W, bias, out);
}